// Round 13
// baseline (1832.927 us; speedup 1.0000x reference)
//
#include <hip/hip_runtime.h>
#include <stdint.h>

// Problem constants
#define HID 100
#define B_TOTAL 512
#define T_IN 1000
#define NB 2
#define BLOCK 512   // 8 waves, 2 waves/EU

typedef __fp16 f16x8 __attribute__((ext_vector_type(8)));
typedef float f32x4 __attribute__((ext_vector_type(4)));

#define MF(A, B, C) __builtin_amdgcn_mfma_f32_16x16x32_f16((A), (B), (C), 0, 0, 0)

// ---- fast activation math (R11/R12-verified: absmax unchanged) ----
#if __has_builtin(__builtin_amdgcn_exp2f)
#define EXP2F(x) __builtin_amdgcn_exp2f(x)
#else
#define EXP2F(x) exp2f(x)
#endif
#if __has_builtin(__builtin_amdgcn_rcpf)
#define RCPF(x) __builtin_amdgcn_rcpf(x)
#else
#define RCPF(x) (1.0f / (x))
#endif
#define LOG2E 1.44269504f
__device__ __forceinline__ float sigm(float x) { return RCPF(1.0f + EXP2F(-LOG2E * x)); }
__device__ __forceinline__ float tanh_fast(float x) {
  return 1.0f - 2.0f * RCPF(EXP2F((2.0f * LOG2E) * x) + 1.0f);
}

// ---- compact A layout (R8-verified): per 32-K tile, 80 f16 ----
__device__ __forceinline__ int cidx(int k, int m) {
  return (k >> 5) * 80 + m * 32 + (k & 31);
}

// weight element fetchers (R8-verified)
__device__ __forceinline__ __fp16 w1e(const float* Whh1, const float* Wih1, int j, int k) {
  float v = 0.0f;
  if (k < 100) v = Whh1[j * 100 + k];
  else if (k == 100) v = Wih1[j];
  return (__fp16)v;
}
__device__ __forceinline__ __fp16 w2e(const float* Wih2, const float* Whh2, int j, int k) {
  float v = 0.0f;
  if (k < 100) v = Wih2[j * 100 + k];
  else if (k >= 112 && k < 212) v = Whh2[j * 100 + (k - 112)];
  return (__fp16)v;
}

#define MKB1(J, KT) (f16x8){ \
  w1e(Whh1, Wih1, (J), (KT)*32 + kg*8 + 0), w1e(Whh1, Wih1, (J), (KT)*32 + kg*8 + 1), \
  w1e(Whh1, Wih1, (J), (KT)*32 + kg*8 + 2), w1e(Whh1, Wih1, (J), (KT)*32 + kg*8 + 3), \
  w1e(Whh1, Wih1, (J), (KT)*32 + kg*8 + 4), w1e(Whh1, Wih1, (J), (KT)*32 + kg*8 + 5), \
  w1e(Whh1, Wih1, (J), (KT)*32 + kg*8 + 6), w1e(Whh1, Wih1, (J), (KT)*32 + kg*8 + 7) }
#define MKB2(J, KT) (f16x8){ \
  w2e(Wih2, Whh2, (J), (KT)*32 + kg*8 + 0), w2e(Wih2, Whh2, (J), (KT)*32 + kg*8 + 1), \
  w2e(Wih2, Whh2, (J), (KT)*32 + kg*8 + 2), w2e(Wih2, Whh2, (J), (KT)*32 + kg*8 + 3), \
  w2e(Wih2, Whh2, (J), (KT)*32 + kg*8 + 4), w2e(Wih2, Whh2, (J), (KT)*32 + kg*8 + 5), \
  w2e(Wih2, Whh2, (J), (KT)*32 + kg*8 + 6), w2e(Wih2, Whh2, (J), (KT)*32 + kg*8 + 7) }

__global__ __launch_bounds__(BLOCK, 2) void lstm2_mfma(
    const float* __restrict__ input,  // [512,1000]
    const float* __restrict__ Wih1,   // [400,1]
    const float* __restrict__ Whh1,   // [400,100]
    const float* __restrict__ bih1,
    const float* __restrict__ bhh1,
    const float* __restrict__ Wih2,   // [400,100]
    const float* __restrict__ Whh2,   // [400,100]
    const float* __restrict__ bih2,
    const float* __restrict__ bhh2,
    const float* __restrict__ Wlin,   // [1,100]
    const float* __restrict__ blin,   // [1]
    const int* __restrict__ futp,
    float* __restrict__ out)          // [512, 1000+future]
{
  __shared__ __align__(16) __fp16 A1c[4 * 80];    // L1 A: k0..99=h1(t-1), k100=x(t)
  __shared__ __align__(16) __fp16 A2c[7 * 80];    // L2 A: k0..99=h1, k112..211=h2
  __shared__ __align__(16) __fp16 BL1h[4 * 512];  // B frags, N-tile 24 (wave 0)
  __shared__ __align__(16) __fp16 BL2h[7 * 512];
  __shared__ float2 gbA[400];        // L1 gate pre-acts [n](b0,b1)
  __shared__ float2 gbB[400];        // L2 gate pre-acts
  __shared__ float xrow[NB][T_IN];   // staged inputs (8 KB)
  __shared__ float ybuf[NB][104];    // h2(t) f32 for y-dot (pads 0)
  __shared__ float wls[104];         // Wlin staged (pads 0)

  const int tid = threadIdx.x;
  const int lane = tid & 63;
  const int wv = tid >> 6;
  const int b0 = blockIdx.x * NB;
  const int F = futp[0];
  const int TT = T_IN + F;

  // ---------------- init: stage + zero ----------------
  for (int i = tid; i < NB * T_IN; i += BLOCK) {
    int b = i / T_IN, t = i % T_IN;
    xrow[b][t] = input[(size_t)(b0 + b) * T_IN + t];
  }
  if (tid < 160) ((uint32_t*)A1c)[tid] = 0u;
  if (tid < 280) ((uint32_t*)A2c)[tid] = 0u;
  if (tid < 104) wls[tid] = (tid < HID) ? Wlin[tid] : 0.0f;
  if (tid < 208) ((float*)ybuf)[tid] = 0.0f;

  // ---------------- register-resident B fragments (R8-verified) ----------------
  const int n15 = lane & 15;
  const int kg = (lane >> 4) & 3;
  const int j0 = (wv) * 16 + n15;
  const int j1 = (8 + wv) * 16 + n15;
  const int j2 = (16 + wv) * 16 + n15;
  f16x8 B1_0_0 = MKB1(j0, 0), B1_0_1 = MKB1(j0, 1), B1_0_2 = MKB1(j0, 2), B1_0_3 = MKB1(j0, 3);
  f16x8 B1_1_0 = MKB1(j1, 0), B1_1_1 = MKB1(j1, 1), B1_1_2 = MKB1(j1, 2), B1_1_3 = MKB1(j1, 3);
  f16x8 B1_2_0 = MKB1(j2, 0), B1_2_1 = MKB1(j2, 1), B1_2_2 = MKB1(j2, 2), B1_2_3 = MKB1(j2, 3);
  f16x8 B2_0_0 = MKB2(j0, 0), B2_0_1 = MKB2(j0, 1), B2_0_2 = MKB2(j0, 2), B2_0_3 = MKB2(j0, 3),
        B2_0_4 = MKB2(j0, 4), B2_0_5 = MKB2(j0, 5), B2_0_6 = MKB2(j0, 6);
  f16x8 B2_1_0 = MKB2(j1, 0), B2_1_1 = MKB2(j1, 1), B2_1_2 = MKB2(j1, 2), B2_1_3 = MKB2(j1, 3),
        B2_1_4 = MKB2(j1, 4), B2_1_5 = MKB2(j1, 5), B2_1_6 = MKB2(j1, 6);
  f16x8 B2_2_0 = MKB2(j2, 0), B2_2_1 = MKB2(j2, 1), B2_2_2 = MKB2(j2, 2), B2_2_3 = MKB2(j2, 3),
        B2_2_4 = MKB2(j2, 4), B2_2_5 = MKB2(j2, 5), B2_2_6 = MKB2(j2, 6);

  // N-tile 24 fragments -> LDS (tids 0..63 emulate one wave's lanes; R8-verified)
  if (tid < 64) {
    int jj = 384 + n15;
    f16x8* BV1 = (f16x8*)BL1h;
    f16x8* BV2 = (f16x8*)BL2h;
    BV1[0 * 64 + tid] = MKB1(jj, 0); BV1[1 * 64 + tid] = MKB1(jj, 1);
    BV1[2 * 64 + tid] = MKB1(jj, 2); BV1[3 * 64 + tid] = MKB1(jj, 3);
    BV2[0 * 64 + tid] = MKB2(jj, 0); BV2[1 * 64 + tid] = MKB2(jj, 1);
    BV2[2 * 64 + tid] = MKB2(jj, 2); BV2[3 * 64 + tid] = MKB2(jj, 3);
    BV2[4 * 64 + tid] = MKB2(jj, 4); BV2[5 * 64 + tid] = MKB2(jj, 5);
    BV2[6 * 64 + tid] = MKB2(jj, 6);
  }

  const int roff = (n15 < 2) ? (n15 * 32 + kg * 8) : 64;

  // ---------------- act duty: tids 256..455 -> (b, k) ----------------
  const int is_act = (tid >= 256 && tid < 256 + NB * HID);
  const int ab = (tid - 256) & 1;
  const int ak = (tid - 256) >> 1;
  float b1i = 0, b1f = 0, b1g = 0, b1o = 0, b2i = 0, b2f = 0, b2g = 0, b2o = 0;
  if (is_act) {
    b1i = bih1[ak] + bhh1[ak];             b1f = bih1[ak + 100] + bhh1[ak + 100];
    b1g = bih1[ak + 200] + bhh1[ak + 200]; b1o = bih1[ak + 300] + bhh1[ak + 300];
    b2i = bih2[ak] + bhh2[ak];             b2f = bih2[ak + 100] + bhh2[ak + 100];
    b2g = bih2[ak + 200] + bhh2[ak + 200]; b2o = bih2[ak + 300] + bhh2[ak + 300];
  }
  float c1v = 0.0f, c2v = 0.0f;

  // ---------------- y duty: tids 496..511 ----------------
  const int is_y = (tid >= 496);
  const int ybat = ((tid - 496) >> 3) & 1;
  const int yl = (tid - 496) & 7;
  const float blin0 = blin[0];

  __syncthreads();
  if (tid >= 464 && tid < 466) A1c[cidx(100, tid - 464)] = (__fp16)xrow[tid - 464][0];
  __syncthreads();

#define RDA(BUF, t) (*(const f16x8*)&(BUF)[(t) * 80 + roff])

  // held W3-partials (live across one barrier) + prefetched A1 frags
  f32x4 pA, pB, pC, p24;
  f16x8 pa0 = RDA(A1c, 0), pa1 = RDA(A1c, 1), pa2 = RDA(A1c, 2), pa3 = RDA(A1c, 3);

// W1(t) -> gbA. Zero LDS reads (register pa frags) except wave0's static B-tile.
#define W1_PHASE { \
    f32x4 c0 = {0.f,0.f,0.f,0.f}, c1 = {0.f,0.f,0.f,0.f}, c2 = {0.f,0.f,0.f,0.f}; \
    c0 = MF(pa0, B1_0_0, c0); c0 = MF(pa1, B1_0_1, c0); c0 = MF(pa2, B1_0_2, c0); c0 = MF(pa3, B1_0_3, c0); \
    c1 = MF(pa0, B1_1_0, c1); c1 = MF(pa1, B1_1_1, c1); c1 = MF(pa2, B1_1_2, c1); c1 = MF(pa3, B1_1_3, c1); \
    c2 = MF(pa0, B1_2_0, c2); c2 = MF(pa1, B1_2_1, c2); c2 = MF(pa2, B1_2_2, c2); c2 = MF(pa3, B1_2_3, c2); \
    if (wv == 0) { \
      const f16x8* Bv1 = (const f16x8*)BL1h; \
      f32x4 c3 = {0.f,0.f,0.f,0.f}; \
      c3 = MF(pa0, Bv1[lane], c3); c3 = MF(pa1, Bv1[64 + lane], c3); \
      c3 = MF(pa2, Bv1[128 + lane], c3); c3 = MF(pa3, Bv1[192 + lane], c3); \
      if (lane < 16) gbA[384 + lane] = float2{c3[0], c3[1]}; \
    } \
    if (lane < 16) { \
      gbA[(wv << 4) + lane] = float2{c0[0], c0[1]}; \
      gbA[((8 + wv) << 4) + lane] = float2{c1[0], c1[1]}; \
      gbA[((16 + wv) << 4) + lane] = float2{c2[0], c2[1]}; \
    } }

// W3-part(t): reads h2(t-1) tiles 4..6; partials held in regs across next barrier.
#define W3_PHASE { \
    f16x8 z4 = RDA(A2c, 4), z5 = RDA(A2c, 5), z6 = RDA(A2c, 6); \
    pA = (f32x4){0.f,0.f,0.f,0.f}; pB = (f32x4){0.f,0.f,0.f,0.f}; pC = (f32x4){0.f,0.f,0.f,0.f}; \
    pA = MF(z4, B2_0_4, pA); pA = MF(z5, B2_0_5, pA); pA = MF(z6, B2_0_6, pA); \
    pB = MF(z4, B2_1_4, pB); pB = MF(z5, B2_1_5, pB); pB = MF(z6, B2_1_6, pB); \
    pC = MF(z4, B2_2_4, pC); pC = MF(z5, B2_2_5, pC); pC = MF(z6, B2_2_6, pC); \
    if (wv == 0) { \
      const f16x8* Bv2 = (const f16x8*)BL2h; \
      p24 = (f32x4){0.f,0.f,0.f,0.f}; \
      p24 = MF(z4, Bv2[256 + lane], p24); p24 = MF(z5, Bv2[320 + lane], p24); \
      p24 = MF(z6, Bv2[384 + lane], p24); \
    } }

// G2(t): frags 0..3 over h1(t) tiles, C-init = held partials -> gbB.
#define L2_PHASE { \
    f16x8 n0 = RDA(A2c, 0), n1 = RDA(A2c, 1), n2 = RDA(A2c, 2), n3 = RDA(A2c, 3); \
    f32x4 d0 = pA, d1 = pB, d2 = pC; \
    d0 = MF(n0, B2_0_0, d0); d0 = MF(n1, B2_0_1, d0); d0 = MF(n2, B2_0_2, d0); d0 = MF(n3, B2_0_3, d0); \
    d1 = MF(n0, B2_1_0, d1); d1 = MF(n1, B2_1_1, d1); d1 = MF(n2, B2_1_2, d1); d1 = MF(n3, B2_1_3, d1); \
    d2 = MF(n0, B2_2_0, d2); d2 = MF(n1, B2_2_1, d2); d2 = MF(n2, B2_2_2, d2); d2 = MF(n3, B2_2_3, d2); \
    if (wv == 0) { \
      const f16x8* Bv2 = (const f16x8*)BL2h; \
      f32x4 d3 = p24; \
      d3 = MF(n0, Bv2[lane], d3); d3 = MF(n1, Bv2[64 + lane], d3); \
      d3 = MF(n2, Bv2[128 + lane], d3); d3 = MF(n3, Bv2[192 + lane], d3); \
      if (lane < 16) gbB[384 + lane] = float2{d3[0], d3[1]}; \
    } \
    if (lane < 16) { \
      gbB[(wv << 4) + lane] = float2{d0[0], d0[1]}; \
      gbB[((8 + wv) << 4) + lane] = float2{d1[0], d1[1]}; \
      gbB[((16 + wv) << 4) + lane] = float2{d2[0], d2[1]}; \
    } }

#define ACT1_BODY { \
    const float* gbf = (const float*)gbA; \
    float gi = gbf[(ak) * 2 + ab] + b1i; \
    float gf = gbf[(ak + 100) * 2 + ab] + b1f; \
    float gg = gbf[(ak + 200) * 2 + ab] + b1g; \
    float go = gbf[(ak + 300) * 2 + ab] + b1o; \
    c1v = sigm(gf) * c1v + sigm(gi) * tanh_fast(gg); \
    __fp16 h = (__fp16)(sigm(go) * tanh_fast(c1v)); \
    A1c[cidx(ak, ab)] = h; A2c[cidx(ak, ab)] = h; }

#define ACT2_BODY { \
    const float* gbf = (const float*)gbB; \
    float gi = gbf[(ak) * 2 + ab] + b2i; \
    float gf = gbf[(ak + 100) * 2 + ab] + b2f; \
    float gg = gbf[(ak + 200) * 2 + ab] + b2g; \
    float go = gbf[(ak + 300) * 2 + ab] + b2o; \
    c2v = sigm(gf) * c2v + sigm(gi) * tanh_fast(gg); \
    float hv = sigm(go) * tanh_fast(c2v); \
    A2c[cidx(112 + ak, ab)] = (__fp16)hv; ybuf[ab][ak] = hv; }

#define Y_BODY(tt, FEED) { \
    float s = 0.0f; \
    _Pragma("unroll") \
    for (int m = 0; m < 13; m++) s = fmaf(ybuf[ybat][yl + 8 * m], wls[yl + 8 * m], s); \
    s += __shfl_down(s, 4, 8); \
    s += __shfl_down(s, 2, 8); \
    s += __shfl_down(s, 1, 8); \
    if (yl == 0) { \
      float y = s + blin0; \
      out[(size_t)(b0 + ybat) * TT + (tt)] = y; \
      if (FEED) A1c[cidx(100, ybat)] = (__fp16)y; \
    } }

  // ============ teacher-forced: 3 barriers/step, acts overlapped ============
  // invariant at loop top: pa = h1(t-1)+x(t) frags; gbB = L2 gates(t-1);
  // ACT2(t-1) pending; A2c tiles4-6 = h2(t-2).
  for (int t = 0; t < T_IN; t++) {
    // P1: W1(t) -> gbA  ||  ACT2(t-1): h2(t-1) -> A2c tiles4-6, ybuf
    W1_PHASE
    if (is_act && t > 0) ACT2_BODY
    __syncthreads();  // A: gbA ready; h2(t-1), ybuf(t-1) ready
    // P2: W3-part(t) over fresh h2(t-1)  ||  ACT1(t) from gbA  ||  y(t-1), x(t+1)
    W3_PHASE
    if (is_act) ACT1_BODY
    if (tid >= 464 && tid < 466 && t + 1 < T_IN)
      A1c[cidx(100, tid - 464)] = (__fp16)xrow[tid - 464][t + 1];
    if (is_y && t > 0) Y_BODY(t - 1, 0)
    __syncthreads();  // B: h1(t) in A1c/A2c; x(t+1) staged
    // P3: G2(t) -> gbB ; prefetch next step's A1 frags
    L2_PHASE
    pa0 = RDA(A1c, 0); pa1 = RDA(A1c, 1); pa2 = RDA(A1c, 2); pa3 = RDA(A1c, 3);
    __syncthreads();  // C: gbB ready
  }

  // ---- TF->AR handoff: ACT2(T_IN-1) was left pending ----
  if (is_act) ACT2_BODY
  __syncthreads();    // h2(T_IN-1), ybuf(T_IN-1) ready

  // ================= autoregressive: 5 barriers/step =================
  for (int t = T_IN; t < TT; t++) {
    if (is_y) Y_BODY(t - 1, 1)            // y(t-1) -> out + x(t) feed into A1
    __syncthreads();  // x(t) ready
    pa0 = RDA(A1c, 0); pa1 = RDA(A1c, 1); pa2 = RDA(A1c, 2); pa3 = RDA(A1c, 3);
    W1_PHASE
    W3_PHASE          // h2(t-1) valid (ACT2(t-1) done before loop / prev iter)
    __syncthreads();  // gbA ready
    if (is_act) ACT1_BODY
    __syncthreads();  // h1(t) ready
    L2_PHASE
    __syncthreads();  // gbB ready
    if (is_act) ACT2_BODY
    __syncthreads();  // ybuf(t) stable for next Y
  }
  if (is_y) Y_BODY(TT - 1, 0)             // final y
}

extern "C" void kernel_launch(void* const* d_in, const int* in_sizes, int n_in,
                              void* d_out, int out_size, void* d_ws, size_t ws_size,
                              hipStream_t stream) {
  const float* input = (const float*)d_in[0];
  const float* Wih1  = (const float*)d_in[1];
  const float* Whh1  = (const float*)d_in[2];
  const float* bih1  = (const float*)d_in[3];
  const float* bhh1  = (const float*)d_in[4];
  const float* Wih2  = (const float*)d_in[5];
  const float* Whh2  = (const float*)d_in[6];
  const float* bih2  = (const float*)d_in[7];
  const float* bhh2  = (const float*)d_in[8];
  const float* Wlin  = (const float*)d_in[9];
  const float* blin  = (const float*)d_in[10];
  const int*   futp  = (const int*)d_in[11];
  float* out = (float*)d_out;

  dim3 grid(B_TOTAL / NB);  // 256 blocks, 1 per CU
  dim3 block(BLOCK);
  hipLaunchKernelGGL(lstm2_mfma, grid, block, 0, stream,
                     input, Wih1, Whh1, bih1, bhh1, Wih2, Whh2, bih2, bhh2,
                     Wlin, blin, futp, out);
}